// Round 7
// baseline (370.585 us; speedup 1.0000x reference)
//
#include <hip/hip_runtime.h>

#define NN 50000
#define NE 800000
#define DF 128
#define BM 32
#define NB ((NN + BM - 1) / BM)   // 1563

typedef __attribute__((ext_vector_type(8))) short bf16x8;
typedef __attribute__((ext_vector_type(4))) float f32x4;

// ---- workspace layout (bytes) ----
static const size_t OFF_DEG  = 0;         // u32[NN]
static const size_t OFF_OFFS = 204800;    // u32[NN+1]
static const size_t OFF_RANK = 409600;    // u32[NE]
static const size_t OFF_CSR  = 3609600;   // int2[NE]
static const size_t OFF_WT   = 10009600;  // bf16 Wt[256][128]
static const size_t OFF_WET  = 10075136;  // bf16 WeT[128][128]
static const size_t OFF_P1   = 10107904;  // f32[50048*128]
static const size_t OFF_P2   = 35732480;  // bf16[50048*128]

__device__ __forceinline__ unsigned f2bf(float f) {
    unsigned u = __float_as_uint(f);
    return (u + 0x7FFFu + ((u >> 16) & 1u)) >> 16;
}
__device__ __forceinline__ f32x4 ntload4(const float* p) {
    return __builtin_nontemporal_load(reinterpret_cast<const f32x4*>(p));
}

// zero deg + build Wt / WeT (bf16 transposed weights)
__global__ void k_setup(const float* __restrict__ W, const float* __restrict__ We,
                        unsigned* __restrict__ deg, unsigned short* __restrict__ Wt,
                        unsigned short* __restrict__ WeT) {
    int idx = blockIdx.x * blockDim.x + threadIdx.x;
    if (idx < NN) deg[idx] = 0;
    if (idx < 256 * 128) {
        int n = idx >> 7, k = idx & 127;
        Wt[idx] = (unsigned short)f2bf(W[k * 256 + n]);
    }
    if (idx < 128 * 128) {
        int n = idx >> 7, k = idx & 127;
        WeT[idx] = (unsigned short)f2bf(We[k * 128 + n]);
    }
}

__global__ void k_hist(const int* __restrict__ rcv, unsigned* __restrict__ deg,
                       unsigned* __restrict__ rank) {
    int e = blockIdx.x * blockDim.x + threadIdx.x;
    if (e < NE) rank[e] = atomicAdd(&deg[rcv[e]], 1u);
}

// single-kernel exclusive scan: 1024 threads, 49 elems/thread (chunked)
#define SPT 49
__global__ __launch_bounds__(1024) void k_scan(const unsigned* __restrict__ deg,
                                               unsigned* __restrict__ offs) {
    __shared__ unsigned wtot[16], wbase[16];
    const int t = threadIdx.x;
    const int w = t >> 6, lane = t & 63;
    const int base = t * SPT;
    unsigned s = 0;
#pragma unroll 7
    for (int i = 0; i < SPT; ++i) {
        int idx = base + i;
        if (idx < NN) s += deg[idx];
    }
    unsigned x = s;
#pragma unroll
    for (int o = 1; o < 64; o <<= 1) {
        unsigned y = __shfl_up(x, o);
        if (lane >= o) x += y;
    }
    if (lane == 63) wtot[w] = x;
    __syncthreads();
    if (t == 0) {
        unsigned run = 0;
        for (int i = 0; i < 16; ++i) { unsigned v = wtot[i]; wbase[i] = run; run += v; }
    }
    __syncthreads();
    unsigned run = wbase[w] + x - s;  // exclusive prefix for this thread
#pragma unroll 7
    for (int i = 0; i < SPT; ++i) {
        int idx = base + i;
        if (idx < NN) { offs[idx] = run; run += deg[idx]; }
    }
    if (t == 1023) offs[NN] = run;  // == NE
}

__global__ void k_scatter(const int* __restrict__ snd, const int* __restrict__ rcv,
                          const unsigned* __restrict__ offs, const unsigned* __restrict__ rank,
                          int2* __restrict__ csr) {
    int e = blockIdx.x * blockDim.x + threadIdx.x;
    if (e >= NE) return;
    csr[offs[rcv[e]] + rank[e]] = make_int2(snd[e], e);
}

// P1 = X@W[:, :128] (fp32), P2 = bf16(X@W[:, 128:]); 64 rows/block, 4 waves
__global__ __launch_bounds__(256) void k_gemm1(
    const float* __restrict__ X, const unsigned short* __restrict__ Wt,
    float* __restrict__ P1, unsigned short* __restrict__ P2) {
    __shared__ unsigned short As[64 * 128];  // 16 KiB, XOR-swizzled
    const int tid = threadIdx.x;
    const int w = tid >> 6, lane = tid & 63;
    const int l15 = lane & 15, l4 = lane >> 4;
    const int m0 = blockIdx.x * 64;
    char* Asb = (char*)As;

    for (int i = tid; i < 64 * 32; i += 256) {
        int r = i >> 5, g = i & 31;
        int n = m0 + r;
        f32x4 v = {0.f, 0.f, 0.f, 0.f};
        if (n < NN) v = *reinterpret_cast<const f32x4*>(X + (size_t)n * DF + g * 4);
        unsigned pk0 = f2bf(v[0]) | (f2bf(v[1]) << 16);
        unsigned pk1 = f2bf(v[2]) | (f2bf(v[3]) << 16);
        unsigned byte = (unsigned)(r * 256 + g * 8) ^ ((unsigned)(r & 7) << 4);
        *reinterpret_cast<uint2*>(Asb + byte) = make_uint2(pk0, pk1);
    }
    __syncthreads();

    const int rrow = w * 16 + l15;
    const unsigned rswz = (unsigned)(rrow & 7) << 4;
    f32x4 acc[16];
#pragma unroll
    for (int ng = 0; ng < 16; ++ng) acc[ng] = (f32x4){0.f, 0.f, 0.f, 0.f};
#pragma unroll
    for (int kk = 0; kk < 4; ++kk) {
        unsigned abyte = (unsigned)(rrow * 256 + (kk * 32 + l4 * 8) * 2) ^ rswz;
        bf16x8 a = *reinterpret_cast<const bf16x8*>(Asb + abyte);
#pragma unroll
        for (int ng = 0; ng < 16; ++ng) {
            bf16x8 b = *reinterpret_cast<const bf16x8*>(
                Wt + (size_t)(ng * 16 + l15) * 128 + kk * 32 + l4 * 8);
            acc[ng] = __builtin_amdgcn_mfma_f32_16x16x32_bf16(a, b, acc[ng], 0, 0, 0);
        }
    }
#pragma unroll
    for (int ng = 0; ng < 16; ++ng) {
        int col = ng * 16 + l15;
#pragma unroll
        for (int j = 0; j < 4; ++j) {
            int row = m0 + w * 16 + l4 * 4 + j;
            if (row < NN) {
                if (col < 128) P1[(size_t)row * DF + col] = acc[ng][j];
                else P2[(size_t)row * DF + (col - 128)] = (unsigned short)f2bf(acc[ng][j]);
            }
        }
    }
}

// fused: per 32-node tile, aggregate P2[senders] (fp32 -> XJ LDS) and EF[edges]
// (-> bf16 AeS LDS), then MFMA AeS@WeT; out = P1 + XJ + Ae@WeT + biases
// phase A: wave owns 4 nodes; 8-lane group per edge (8 chains, x2 unroll = 16 in flight)
__global__ __launch_bounds__(512) void k_aggemm(
    const float* __restrict__ EF, const unsigned short* __restrict__ P2,
    const float* __restrict__ P1, const unsigned* __restrict__ offs,
    const int2* __restrict__ csr, const unsigned short* __restrict__ WeT,
    const float* __restrict__ bW, const float* __restrict__ bWe,
    float* __restrict__ out) {
    __shared__ unsigned short AeS[BM * 128];  // 8 KiB, XOR-swizzled
    __shared__ float XJ[BM][128];             // 16 KiB
    __shared__ float cf_s[BM];
    const int tid = threadIdx.x;
    const int w = tid >> 6, lane = tid & 63;
    const int m0 = blockIdx.x * BM;
    char* Asb = (char*)AeS;

    // ---- phase A ----
    {
        const int g = lane >> 3;       // group 0..7: one edge per trip
        const int gl = lane & 7;       // lane in group
        const int c16 = gl * 16;       // 16 cols per lane
        for (int t = 0; t < 4; ++t) {
            int r = w * 4 + t;
            int n = m0 + r;
            unsigned s0 = 0, s1 = 0;
            if (n < NN) { s0 = offs[n]; s1 = offs[n + 1]; }
            s0 = __builtin_amdgcn_readfirstlane(s0);
            s1 = __builtin_amdgcn_readfirstlane(s1);
            unsigned dg = s1 - s0;
            f32x4 ef[4], xj[4];
#pragma unroll
            for (int i = 0; i < 4; ++i) {
                ef[i] = (f32x4){0.f, 0.f, 0.f, 0.f};
                xj[i] = (f32x4){0.f, 0.f, 0.f, 0.f};
            }
            unsigned trips = (dg + 7) >> 3;
            unsigned p = s0 + g;
#pragma unroll 2
            for (unsigned it = 0; it < trips; ++it, p += 8) {
                bool act = p < s1;
                unsigned pc = act ? p : s0;
                int2 se = csr[pc];
                const float* er = EF + (size_t)se.y * DF + c16;
                f32x4 e0 = ntload4(er);
                f32x4 e1 = ntload4(er + 4);
                f32x4 e2 = ntload4(er + 8);
                f32x4 e3 = ntload4(er + 12);
                const unsigned short* pr = P2 + (size_t)se.x * DF + c16;
                uint4 pu0 = *reinterpret_cast<const uint4*>(pr);
                uint4 pu1 = *reinterpret_cast<const uint4*>(pr + 8);
                float m = act ? 1.f : 0.f;
                ef[0] += m * e0; ef[1] += m * e1; ef[2] += m * e2; ef[3] += m * e3;
                xj[0][0] += m * __uint_as_float(pu0.x << 16);
                xj[0][1] += m * __uint_as_float(pu0.x & 0xFFFF0000u);
                xj[0][2] += m * __uint_as_float(pu0.y << 16);
                xj[0][3] += m * __uint_as_float(pu0.y & 0xFFFF0000u);
                xj[1][0] += m * __uint_as_float(pu0.z << 16);
                xj[1][1] += m * __uint_as_float(pu0.z & 0xFFFF0000u);
                xj[1][2] += m * __uint_as_float(pu0.w << 16);
                xj[1][3] += m * __uint_as_float(pu0.w & 0xFFFF0000u);
                xj[2][0] += m * __uint_as_float(pu1.x << 16);
                xj[2][1] += m * __uint_as_float(pu1.x & 0xFFFF0000u);
                xj[2][2] += m * __uint_as_float(pu1.y << 16);
                xj[2][3] += m * __uint_as_float(pu1.y & 0xFFFF0000u);
                xj[3][0] += m * __uint_as_float(pu1.z << 16);
                xj[3][1] += m * __uint_as_float(pu1.z & 0xFFFF0000u);
                xj[3][2] += m * __uint_as_float(pu1.w << 16);
                xj[3][3] += m * __uint_as_float(pu1.w & 0xFFFF0000u);
            }
            // reduce across 8 groups
#pragma unroll
            for (int i = 0; i < 4; ++i)
#pragma unroll
                for (int j = 0; j < 4; ++j) {
                    float a = ef[i][j], b = xj[i][j];
                    a += __shfl_xor(a, 8);  b += __shfl_xor(b, 8);
                    a += __shfl_xor(a, 16); b += __shfl_xor(b, 16);
                    a += __shfl_xor(a, 32); b += __shfl_xor(b, 32);
                    ef[i][j] = a; xj[i][j] = b;
                }
            float inv = 1.0f / ((float)dg + 1e-6f);
            if (g == 0) {  // lanes 0..7 write Ae -> bf16 LDS (swizzled)
#pragma unroll
                for (int i = 0; i < 4; ++i) ef[i] *= inv;
                uint4 pka, pkb;
                pka.x = f2bf(ef[0][0]) | (f2bf(ef[0][1]) << 16);
                pka.y = f2bf(ef[0][2]) | (f2bf(ef[0][3]) << 16);
                pka.z = f2bf(ef[1][0]) | (f2bf(ef[1][1]) << 16);
                pka.w = f2bf(ef[1][2]) | (f2bf(ef[1][3]) << 16);
                pkb.x = f2bf(ef[2][0]) | (f2bf(ef[2][1]) << 16);
                pkb.y = f2bf(ef[2][2]) | (f2bf(ef[2][3]) << 16);
                pkb.z = f2bf(ef[3][0]) | (f2bf(ef[3][1]) << 16);
                pkb.w = f2bf(ef[3][2]) | (f2bf(ef[3][3]) << 16);
                unsigned swz = (unsigned)(r & 7) << 4;
                unsigned b0 = (unsigned)(r * 256 + c16 * 2) ^ swz;
                unsigned b1 = (unsigned)(r * 256 + c16 * 2 + 16) ^ swz;
                *reinterpret_cast<uint4*>(Asb + b0) = pka;
                *reinterpret_cast<uint4*>(Asb + b1) = pkb;
            } else if (g == 1) {  // lanes 8..15 write XJ (fp32)
#pragma unroll
                for (int i = 0; i < 4; ++i) {
                    xj[i] *= inv;
                    *reinterpret_cast<f32x4*>(&XJ[r][c16 + i * 4]) = xj[i];
                }
            }
            if (lane == 0) cf_s[r] = (float)dg * inv;
        }
    }
    __syncthreads();

    // ---- phase C: Ae @ WeT; wave: 16 rows x 32 cols, K=128 ----
    {
        const int l15 = lane & 15, l4 = lane >> 4;
        const int h = w & 1;
        const int rrow = h * 16 + l15;
        const int n0 = (w >> 1) * 32;
        f32x4 acc[2];
        acc[0] = (f32x4){0.f, 0.f, 0.f, 0.f};
        acc[1] = (f32x4){0.f, 0.f, 0.f, 0.f};
        const unsigned rswz = (unsigned)(rrow & 7) << 4;
#pragma unroll
        for (int kk = 0; kk < 4; ++kk) {
            unsigned abyte = (unsigned)(rrow * 256 + (kk * 32 + l4 * 8) * 2) ^ rswz;
            bf16x8 a = *reinterpret_cast<const bf16x8*>(Asb + abyte);
            bf16x8 b0 = *reinterpret_cast<const bf16x8*>(
                WeT + (size_t)(n0 + l15) * 128 + kk * 32 + l4 * 8);
            bf16x8 b1 = *reinterpret_cast<const bf16x8*>(
                WeT + (size_t)(n0 + 16 + l15) * 128 + kk * 32 + l4 * 8);
            acc[0] = __builtin_amdgcn_mfma_f32_16x16x32_bf16(a, b0, acc[0], 0, 0, 0);
            acc[1] = __builtin_amdgcn_mfma_f32_16x16x32_bf16(a, b1, acc[1], 0, 0, 0);
        }
#pragma unroll
        for (int ng = 0; ng < 2; ++ng) {
            int col = n0 + ng * 16 + l15;
            float bx = bW[col];
            float bj = bW[128 + col] + bWe[col];
#pragma unroll
            for (int j = 0; j < 4; ++j) {
                int lr = h * 16 + l4 * 4 + j;
                int row = m0 + lr;
                if (row < NN)
                    out[(size_t)row * DF + col] =
                        P1[(size_t)row * DF + col] + XJ[lr][col] +
                        acc[ng][j] + bx + cf_s[lr] * bj;
            }
        }
    }
}

extern "C" void kernel_launch(void* const* d_in, const int* in_sizes, int n_in,
                              void* d_out, int out_size, void* d_ws, size_t ws_size,
                              hipStream_t stream) {
    const float* X   = (const float*)d_in[0];
    const int*   snd = (const int*)d_in[1];
    const int*   rcv = (const int*)d_in[2];
    const float* EF  = (const float*)d_in[3];
    const float* W   = (const float*)d_in[4];
    const float* bW  = (const float*)d_in[5];
    const float* We  = (const float*)d_in[6];
    const float* bWe = (const float*)d_in[7];
    float* out = (float*)d_out;

    char* ws = (char*)d_ws;
    unsigned* deg  = (unsigned*)(ws + OFF_DEG);
    unsigned* offs = (unsigned*)(ws + OFF_OFFS);
    unsigned* rank = (unsigned*)(ws + OFF_RANK);
    int2*     csr  = (int2*)(ws + OFF_CSR);
    unsigned short* Wt  = (unsigned short*)(ws + OFF_WT);
    unsigned short* WeT = (unsigned short*)(ws + OFF_WET);
    float*          P1  = (float*)(ws + OFF_P1);
    unsigned short* P2  = (unsigned short*)(ws + OFF_P2);

    k_setup<<<(NN + 255) / 256, 256, 0, stream>>>(W, We, deg, Wt, WeT);
    k_hist<<<(NE + 255) / 256, 256, 0, stream>>>(rcv, deg, rank);
    k_scan<<<1, 1024, 0, stream>>>(deg, offs);
    k_scatter<<<(NE + 255) / 256, 256, 0, stream>>>(snd, rcv, offs, rank, csr);
    k_gemm1<<<(NN + 63) / 64, 256, 0, stream>>>(X, Wt, P1, P2);
    k_aggemm<<<NB, 512, 0, stream>>>(EF, P2, P1, offs, csr, WeT, bW, bWe, out);
}

// Round 8
// 238.716 us; speedup vs baseline: 1.5524x; 1.5524x over previous
//
#include <hip/hip_runtime.h>

#define NN 50000
#define NE 800000
#define DF 128
#define BM 32
#define NB ((NN + BM - 1) / BM)   // 1563
#define SCAN_B ((NN + 255) / 256) // 196
#define GB ((NN + 63) / 64)       // 782 gemm1 blocks
#define HB ((NE + 255) / 256)     // 3125 hist blocks

typedef __attribute__((ext_vector_type(8))) short bf16x8;
typedef __attribute__((ext_vector_type(4))) float f32x4;

// ---- workspace layout (bytes) ----
static const size_t OFF_DEG  = 0;         // u32[NN]
static const size_t OFF_OFFS = 204800;    // u32[NN+1]
static const size_t OFF_PART = 409600;    // u32[SCAN_B]
static const size_t OFF_RANK = 614400;    // u32[NE]
static const size_t OFF_CSR  = 3814400;   // int2[NE]
static const size_t OFF_WT   = 10214400;  // bf16 Wt[256][128]
static const size_t OFF_WET  = 10279936;  // bf16 WeT[128][128]
static const size_t OFF_P1   = 10312704;  // f32[50048*128]
static const size_t OFF_P2   = 35937280;  // bf16[50048*128]

__device__ __forceinline__ unsigned f2bf(float f) {
    unsigned u = __float_as_uint(f);
    return (u + 0x7FFFu + ((u >> 16) & 1u)) >> 16;
}

// zero deg + build Wt / WeT (bf16 transposed weights)
__global__ void k_setup(const float* __restrict__ W, const float* __restrict__ We,
                        unsigned* __restrict__ deg, unsigned short* __restrict__ Wt,
                        unsigned short* __restrict__ WeT) {
    int idx = blockIdx.x * blockDim.x + threadIdx.x;
    if (idx < NN) deg[idx] = 0;
    if (idx < 256 * 128) {
        int n = idx >> 7, k = idx & 127;
        Wt[idx] = (unsigned short)f2bf(W[k * 256 + n]);
    }
    if (idx < 128 * 128) {
        int n = idx >> 7, k = idx & 127;
        WeT[idx] = (unsigned short)f2bf(We[k * 128 + n]);
    }
}

// fused: blocks [0,GB) compute P1/P2 GEMM; blocks [GB,GB+HB) do degree hist.
// Independent work overlapped in one dispatch.
__global__ __launch_bounds__(256) void k_gemm1hist(
    const float* __restrict__ X, const unsigned short* __restrict__ Wt,
    float* __restrict__ P1, unsigned short* __restrict__ P2,
    const int* __restrict__ rcv, unsigned* __restrict__ deg,
    unsigned* __restrict__ rank) {
    __shared__ unsigned short As[64 * 128];  // 16 KiB, XOR-swizzled
    if (blockIdx.x >= GB) {
        int e = (blockIdx.x - GB) * 256 + threadIdx.x;
        if (e < NE) rank[e] = atomicAdd(&deg[rcv[e]], 1u);
        return;
    }
    const int tid = threadIdx.x;
    const int w = tid >> 6, lane = tid & 63;
    const int l15 = lane & 15, l4 = lane >> 4;
    const int m0 = blockIdx.x * 64;
    char* Asb = (char*)As;

    for (int i = tid; i < 64 * 32; i += 256) {
        int r = i >> 5, g = i & 31;
        int n = m0 + r;
        f32x4 v = {0.f, 0.f, 0.f, 0.f};
        if (n < NN) v = *reinterpret_cast<const f32x4*>(X + (size_t)n * DF + g * 4);
        unsigned pk0 = f2bf(v[0]) | (f2bf(v[1]) << 16);
        unsigned pk1 = f2bf(v[2]) | (f2bf(v[3]) << 16);
        unsigned byte = (unsigned)(r * 256 + g * 8) ^ ((unsigned)(r & 7) << 4);
        *reinterpret_cast<uint2*>(Asb + byte) = make_uint2(pk0, pk1);
    }
    __syncthreads();

    const int rrow = w * 16 + l15;
    const unsigned rswz = (unsigned)(rrow & 7) << 4;
    f32x4 acc[16];
#pragma unroll
    for (int ng = 0; ng < 16; ++ng) acc[ng] = (f32x4){0.f, 0.f, 0.f, 0.f};
#pragma unroll
    for (int kk = 0; kk < 4; ++kk) {
        unsigned abyte = (unsigned)(rrow * 256 + (kk * 32 + l4 * 8) * 2) ^ rswz;
        bf16x8 a = *reinterpret_cast<const bf16x8*>(Asb + abyte);
#pragma unroll
        for (int ng = 0; ng < 16; ++ng) {
            bf16x8 b = *reinterpret_cast<const bf16x8*>(
                Wt + (size_t)(ng * 16 + l15) * 128 + kk * 32 + l4 * 8);
            acc[ng] = __builtin_amdgcn_mfma_f32_16x16x32_bf16(a, b, acc[ng], 0, 0, 0);
        }
    }
#pragma unroll
    for (int ng = 0; ng < 16; ++ng) {
        int col = ng * 16 + l15;
#pragma unroll
        for (int j = 0; j < 4; ++j) {
            int row = m0 + w * 16 + l4 * 4 + j;
            if (row < NN) {
                if (col < 128) P1[(size_t)row * DF + col] = acc[ng][j];
                else P2[(size_t)row * DF + (col - 128)] = (unsigned short)f2bf(acc[ng][j]);
            }
        }
    }
}

__global__ void k_scan1(const unsigned* __restrict__ deg, unsigned* __restrict__ part) {
    int idx = blockIdx.x * 256 + threadIdx.x;
    unsigned v = (idx < NN) ? deg[idx] : 0;
#pragma unroll
    for (int o = 32; o; o >>= 1) v += __shfl_down(v, o);
    __shared__ unsigned wsum[4];
    int w = threadIdx.x >> 6, lane = threadIdx.x & 63;
    if (lane == 0) wsum[w] = v;
    __syncthreads();
    if (threadIdx.x == 0) part[blockIdx.x] = wsum[0] + wsum[1] + wsum[2] + wsum[3];
}

__global__ void k_scan2(unsigned* __restrict__ part, unsigned* __restrict__ offs) {
    __shared__ unsigned sh[SCAN_B];
    int t = threadIdx.x;
    if (t < SCAN_B) sh[t] = part[t];
    __syncthreads();
    if (t == 0) {
        unsigned run = 0;
        for (int i = 0; i < SCAN_B; ++i) { unsigned v = sh[i]; sh[i] = run; run += v; }
        offs[NN] = run;
    }
    __syncthreads();
    if (t < SCAN_B) part[t] = sh[t];
}

__global__ void k_scan3(const unsigned* __restrict__ deg, const unsigned* __restrict__ part,
                        unsigned* __restrict__ offs) {
    int idx = blockIdx.x * 256 + threadIdx.x;
    unsigned v = (idx < NN) ? deg[idx] : 0;
    int w = threadIdx.x >> 6, lane = threadIdx.x & 63;
    unsigned x = v;
#pragma unroll
    for (int o = 1; o < 64; o <<= 1) {
        unsigned y = __shfl_up(x, o);
        if (lane >= o) x += y;
    }
    __shared__ unsigned wsum[4];
    if (lane == 63) wsum[w] = x;
    __syncthreads();
    unsigned base = part[blockIdx.x];
    for (int i = 0; i < w; ++i) base += wsum[i];
    if (idx < NN) offs[idx] = base + x - v;
}

__global__ void k_scatter(const int* __restrict__ snd, const int* __restrict__ rcv,
                          const unsigned* __restrict__ offs, const unsigned* __restrict__ rank,
                          int2* __restrict__ csr) {
    int e = blockIdx.x * blockDim.x + threadIdx.x;
    if (e >= NE) return;
    csr[offs[rcv[e]] + rank[e]] = make_int2(snd[e], e);
}

// fused: per 32-node tile, aggregate P2[senders] (fp32 -> XJ LDS) and EF[edges]
// (-> bf16 AeS LDS), then MFMA AeS@WeT; out = P1 + XJ + Ae@WeT + biases
// phase A: wave owns 4 nodes; 16-lane quarter per edge; all loads contiguous-per-quarter
__global__ __launch_bounds__(512) void k_aggemm(
    const float* __restrict__ EF, const unsigned short* __restrict__ P2,
    const float* __restrict__ P1, const unsigned* __restrict__ offs,
    const int2* __restrict__ csr, const unsigned short* __restrict__ WeT,
    const float* __restrict__ bW, const float* __restrict__ bWe,
    float* __restrict__ out) {
    __shared__ unsigned short AeS[BM * 128];  // 8 KiB, XOR-swizzled
    __shared__ float XJ[BM][128];             // 16 KiB
    __shared__ float cf_s[BM];
    const int tid = threadIdx.x;
    const int w = tid >> 6, lane = tid & 63;
    const int m0 = blockIdx.x * BM;
    char* Asb = (char*)AeS;

    // ---- phase A ----
    {
        const int q = lane >> 4;        // quarter: one edge per trip
        const int l15 = lane & 15;
        const int cA = l15 * 4;         // EF cols cA..cA+3 and 64+cA..64+cA+3
        const int cP = l15 * 8;         // P2 shorts cP..cP+7 (256 B contiguous/quarter)
        for (int t = 0; t < 4; ++t) {
            int r = w * 4 + t;
            int n = m0 + r;
            unsigned s0 = 0, s1 = 0;
            if (n < NN) { s0 = offs[n]; s1 = offs[n + 1]; }
            s0 = __builtin_amdgcn_readfirstlane(s0);
            s1 = __builtin_amdgcn_readfirstlane(s1);
            unsigned dg = s1 - s0;
            f32x4 ef0 = {0.f,0.f,0.f,0.f}, ef1 = {0.f,0.f,0.f,0.f};
            f32x4 xj0 = {0.f,0.f,0.f,0.f}, xj1 = {0.f,0.f,0.f,0.f};
            unsigned trips = (dg + 3) >> 2;
            unsigned p = s0 + q;
#pragma unroll 2
            for (unsigned it = 0; it < trips; ++it, p += 4) {
                bool act = p < s1;
                unsigned pc = act ? p : s0;
                int2 se = csr[pc];
                const float* er = EF + (size_t)se.y * DF;
                f32x4 e0 = *reinterpret_cast<const f32x4*>(er + cA);        // [0,256) B
                f32x4 e1 = *reinterpret_cast<const f32x4*>(er + 64 + cA);   // [256,512) B
                uint4 pu = *reinterpret_cast<const uint4*>(P2 + (size_t)se.x * DF + cP);
                float m = act ? 1.f : 0.f;
                ef0 += m * e0; ef1 += m * e1;
                xj0[0] += m * __uint_as_float(pu.x << 16);
                xj0[1] += m * __uint_as_float(pu.x & 0xFFFF0000u);
                xj0[2] += m * __uint_as_float(pu.y << 16);
                xj0[3] += m * __uint_as_float(pu.y & 0xFFFF0000u);
                xj1[0] += m * __uint_as_float(pu.z << 16);
                xj1[1] += m * __uint_as_float(pu.z & 0xFFFF0000u);
                xj1[2] += m * __uint_as_float(pu.w << 16);
                xj1[3] += m * __uint_as_float(pu.w & 0xFFFF0000u);
            }
#pragma unroll
            for (int i = 0; i < 4; ++i) {
                ef0[i] += __shfl_xor(ef0[i], 16); ef0[i] += __shfl_xor(ef0[i], 32);
                ef1[i] += __shfl_xor(ef1[i], 16); ef1[i] += __shfl_xor(ef1[i], 32);
                xj0[i] += __shfl_xor(xj0[i], 16); xj0[i] += __shfl_xor(xj0[i], 32);
                xj1[i] += __shfl_xor(xj1[i], 16); xj1[i] += __shfl_xor(xj1[i], 32);
            }
            float inv = 1.0f / ((float)dg + 1e-6f);
            unsigned swz = (unsigned)(r & 7) << 4;
            if (q == 0) {  // Ae -> bf16 LDS (swizzled): cols cA and 64+cA
                ef0 *= inv; ef1 *= inv;
                unsigned b0 = (unsigned)(r * 256 + cA * 2) ^ swz;
                unsigned b1 = (unsigned)(r * 256 + (64 + cA) * 2) ^ swz;
                *reinterpret_cast<uint2*>(Asb + b0) =
                    make_uint2(f2bf(ef0[0]) | (f2bf(ef0[1]) << 16),
                               f2bf(ef0[2]) | (f2bf(ef0[3]) << 16));
                *reinterpret_cast<uint2*>(Asb + b1) =
                    make_uint2(f2bf(ef1[0]) | (f2bf(ef1[1]) << 16),
                               f2bf(ef1[2]) | (f2bf(ef1[3]) << 16));
            } else if (q == 1) {  // XJ (fp32): cols cP..cP+7
                xj0 *= inv; xj1 *= inv;
                *reinterpret_cast<f32x4*>(&XJ[r][cP]) = xj0;
                *reinterpret_cast<f32x4*>(&XJ[r][cP + 4]) = xj1;
            }
            if (lane == 0) cf_s[r] = (float)dg * inv;
        }
    }
    __syncthreads();

    // ---- phase C: Ae @ WeT; wave: 16 rows x 32 cols, K=128 ----
    {
        const int l15 = lane & 15, l4 = lane >> 4;
        const int h = w & 1;
        const int rrow = h * 16 + l15;
        const int n0 = (w >> 1) * 32;
        f32x4 acc[2];
        acc[0] = (f32x4){0.f, 0.f, 0.f, 0.f};
        acc[1] = (f32x4){0.f, 0.f, 0.f, 0.f};
        const unsigned rswz = (unsigned)(rrow & 7) << 4;
#pragma unroll
        for (int kk = 0; kk < 4; ++kk) {
            unsigned abyte = (unsigned)(rrow * 256 + (kk * 32 + l4 * 8) * 2) ^ rswz;
            bf16x8 a = *reinterpret_cast<const bf16x8*>(Asb + abyte);
            bf16x8 b0 = *reinterpret_cast<const bf16x8*>(
                WeT + (size_t)(n0 + l15) * 128 + kk * 32 + l4 * 8);
            bf16x8 b1 = *reinterpret_cast<const bf16x8*>(
                WeT + (size_t)(n0 + 16 + l15) * 128 + kk * 32 + l4 * 8);
            acc[0] = __builtin_amdgcn_mfma_f32_16x16x32_bf16(a, b0, acc[0], 0, 0, 0);
            acc[1] = __builtin_amdgcn_mfma_f32_16x16x32_bf16(a, b1, acc[1], 0, 0, 0);
        }
#pragma unroll
        for (int ng = 0; ng < 2; ++ng) {
            int col = n0 + ng * 16 + l15;
            float bx = bW[col];
            float bj = bW[128 + col] + bWe[col];
#pragma unroll
            for (int j = 0; j < 4; ++j) {
                int lr = h * 16 + l4 * 4 + j;
                int row = m0 + lr;
                if (row < NN)
                    out[(size_t)row * DF + col] =
                        P1[(size_t)row * DF + col] + XJ[lr][col] +
                        acc[ng][j] + bx + cf_s[lr] * bj;
            }
        }
    }
}

extern "C" void kernel_launch(void* const* d_in, const int* in_sizes, int n_in,
                              void* d_out, int out_size, void* d_ws, size_t ws_size,
                              hipStream_t stream) {
    const float* X   = (const float*)d_in[0];
    const int*   snd = (const int*)d_in[1];
    const int*   rcv = (const int*)d_in[2];
    const float* EF  = (const float*)d_in[3];
    const float* W   = (const float*)d_in[4];
    const float* bW  = (const float*)d_in[5];
    const float* We  = (const float*)d_in[6];
    const float* bWe = (const float*)d_in[7];
    float* out = (float*)d_out;

    char* ws = (char*)d_ws;
    unsigned* deg  = (unsigned*)(ws + OFF_DEG);
    unsigned* offs = (unsigned*)(ws + OFF_OFFS);
    unsigned* part = (unsigned*)(ws + OFF_PART);
    unsigned* rank = (unsigned*)(ws + OFF_RANK);
    int2*     csr  = (int2*)(ws + OFF_CSR);
    unsigned short* Wt  = (unsigned short*)(ws + OFF_WT);
    unsigned short* WeT = (unsigned short*)(ws + OFF_WET);
    float*          P1  = (float*)(ws + OFF_P1);
    unsigned short* P2  = (unsigned short*)(ws + OFF_P2);

    k_setup<<<(NN + 255) / 256, 256, 0, stream>>>(W, We, deg, Wt, WeT);
    k_gemm1hist<<<GB + HB, 256, 0, stream>>>(X, Wt, P1, P2, rcv, deg, rank);
    k_scan1<<<SCAN_B, 256, 0, stream>>>(deg, part);
    k_scan2<<<1, 256, 0, stream>>>(part, offs);
    k_scan3<<<SCAN_B, 256, 0, stream>>>(deg, part, offs);
    k_scatter<<<(NE + 255) / 256, 256, 0, stream>>>(snd, rcv, offs, rank, csr);
    k_aggemm<<<NB, 512, 0, stream>>>(EF, P2, P1, offs, csr, WeT, bW, bWe, out);
}

// Round 10
// 212.656 us; speedup vs baseline: 1.7427x; 1.1225x over previous
//
#include <hip/hip_runtime.h>

#define NN 50000
#define NE 800000
#define DF 128
#define BM 32
#define NB ((NN + BM - 1) / BM)   // 1563
#define SCAN_B ((NN + 255) / 256) // 196
#define GB ((NN + 63) / 64)       // 782 gemm blocks
#define HB ((NE + 255) / 256)     // 3125 hist blocks

typedef __attribute__((ext_vector_type(8))) short bf16x8;
typedef __attribute__((ext_vector_type(4))) float f32x4;

// ---- workspace layout (bytes) ----
static const size_t OFF_DEG  = 0;         // u32[NN]
static const size_t OFF_OFFS = 204800;    // u32[NN+1]
static const size_t OFF_PART = 409600;    // u32[SCAN_B]
static const size_t OFF_RANK = 614400;    // u32[NE]
static const size_t OFF_CSR  = 3814400;   // int2[NE]
static const size_t OFF_BCTA = 10214400;  // bf16[128][256]: [col][k], k<128=W1, k>=128=We
static const size_t OFF_W2T  = 10279936;  // bf16[128][128]: [col][k] = W[k][128+col]
static const size_t OFF_P2   = 10312704;  // bf16[NN][128] = bf16(X@W[:,128:])
// total ~23.1 MB

__device__ __forceinline__ unsigned f2bf(float f) {
    unsigned u = __float_as_uint(f);
    return (u + 0x7FFFu + ((u >> 16) & 1u)) >> 16;
}

// zero deg + build BcTa (concat [W1; We] transposed) + W2T
__global__ void k_setup(const float* __restrict__ W, const float* __restrict__ We,
                        unsigned* __restrict__ deg, unsigned short* __restrict__ BcTa,
                        unsigned short* __restrict__ W2T) {
    int idx = blockIdx.x * blockDim.x + threadIdx.x;
    if (idx < NN) deg[idx] = 0;
    if (idx < 128 * 256) {
        int col = idx >> 8, k = idx & 255;
        float v = (k < 128) ? W[k * 256 + col] : We[(k - 128) * 128 + col];
        BcTa[idx] = (unsigned short)f2bf(v);
    }
    if (idx < 128 * 128) {
        int col = idx >> 7, k = idx & 127;
        W2T[idx] = (unsigned short)f2bf(W[k * 256 + 128 + col]);
    }
}

// blocks [0,GB): P2 = bf16(X@W[:,128:]); blocks [GB,GB+HB): degree hist + rank
__global__ __launch_bounds__(256) void k_gemm1hist(
    const float* __restrict__ X, const unsigned short* __restrict__ W2T,
    unsigned short* __restrict__ P2, const int* __restrict__ rcv,
    unsigned* __restrict__ deg, unsigned* __restrict__ rank) {
    __shared__ unsigned short As[64 * 128];  // 16 KiB, XOR-swizzled
    if (blockIdx.x >= GB) {
        int e = (blockIdx.x - GB) * 256 + threadIdx.x;
        if (e < NE) rank[e] = atomicAdd(&deg[rcv[e]], 1u);
        return;
    }
    const int tid = threadIdx.x;
    const int w = tid >> 6, lane = tid & 63;
    const int l15 = lane & 15, l4 = lane >> 4;
    const int m0 = blockIdx.x * 64;
    char* Asb = (char*)As;

    for (int i = tid; i < 64 * 32; i += 256) {
        int r = i >> 5, g = i & 31;
        int n = m0 + r;
        f32x4 v = {0.f, 0.f, 0.f, 0.f};
        if (n < NN) v = *reinterpret_cast<const f32x4*>(X + (size_t)n * DF + g * 4);
        unsigned pk0 = f2bf(v[0]) | (f2bf(v[1]) << 16);
        unsigned pk1 = f2bf(v[2]) | (f2bf(v[3]) << 16);
        unsigned byte = (unsigned)(r * 256 + g * 8) ^ ((unsigned)(r & 7) << 4);
        *reinterpret_cast<uint2*>(Asb + byte) = make_uint2(pk0, pk1);
    }
    __syncthreads();

    const int rrow = w * 16 + l15;
    const unsigned rswz = (unsigned)(rrow & 7) << 4;
    f32x4 acc[8];
#pragma unroll
    for (int ng = 0; ng < 8; ++ng) acc[ng] = (f32x4){0.f, 0.f, 0.f, 0.f};
#pragma unroll
    for (int kk = 0; kk < 4; ++kk) {
        unsigned abyte = (unsigned)(rrow * 256 + (kk * 32 + l4 * 8) * 2) ^ rswz;
        bf16x8 a = *reinterpret_cast<const bf16x8*>(Asb + abyte);
#pragma unroll
        for (int ng = 0; ng < 8; ++ng) {
            bf16x8 b = *reinterpret_cast<const bf16x8*>(
                W2T + (size_t)(ng * 16 + l15) * 128 + kk * 32 + l4 * 8);
            acc[ng] = __builtin_amdgcn_mfma_f32_16x16x32_bf16(a, b, acc[ng], 0, 0, 0);
        }
    }
#pragma unroll
    for (int ng = 0; ng < 8; ++ng) {
        int col = ng * 16 + l15;
#pragma unroll
        for (int j = 0; j < 4; ++j) {
            int row = m0 + w * 16 + l4 * 4 + j;
            if (row < NN) P2[(size_t)row * DF + col] = (unsigned short)f2bf(acc[ng][j]);
        }
    }
}

__global__ void k_scan1(const unsigned* __restrict__ deg, unsigned* __restrict__ part) {
    int idx = blockIdx.x * 256 + threadIdx.x;
    unsigned v = (idx < NN) ? deg[idx] : 0;
#pragma unroll
    for (int o = 32; o; o >>= 1) v += __shfl_down(v, o);
    __shared__ unsigned wsum[4];
    int w = threadIdx.x >> 6, lane = threadIdx.x & 63;
    if (lane == 0) wsum[w] = v;
    __syncthreads();
    if (threadIdx.x == 0) part[blockIdx.x] = wsum[0] + wsum[1] + wsum[2] + wsum[3];
}

__global__ void k_scan2(unsigned* __restrict__ part, unsigned* __restrict__ offs) {
    __shared__ unsigned sh[SCAN_B];
    int t = threadIdx.x;
    if (t < SCAN_B) sh[t] = part[t];
    __syncthreads();
    if (t == 0) {
        unsigned run = 0;
        for (int i = 0; i < SCAN_B; ++i) { unsigned v = sh[i]; sh[i] = run; run += v; }
        offs[NN] = run;
    }
    __syncthreads();
    if (t < SCAN_B) part[t] = sh[t];
}

__global__ void k_scan3(const unsigned* __restrict__ deg, const unsigned* __restrict__ part,
                        unsigned* __restrict__ offs) {
    int idx = blockIdx.x * 256 + threadIdx.x;
    unsigned v = (idx < NN) ? deg[idx] : 0;
    int w = threadIdx.x >> 6, lane = threadIdx.x & 63;
    unsigned x = v;
#pragma unroll
    for (int o = 1; o < 64; o <<= 1) {
        unsigned y = __shfl_up(x, o);
        if (lane >= o) x += y;
    }
    __shared__ unsigned wsum[4];
    if (lane == 63) wsum[w] = x;
    __syncthreads();
    unsigned base = part[blockIdx.x];
    for (int i = 0; i < w; ++i) base += wsum[i];
    if (idx < NN) offs[idx] = base + x - v;
}

__global__ void k_scatter(const int* __restrict__ snd, const int* __restrict__ rcv,
                          const unsigned* __restrict__ offs, const unsigned* __restrict__ rank,
                          int2* __restrict__ csr) {
    int e = blockIdx.x * blockDim.x + threadIdx.x;
    if (e >= NE) return;
    csr[offs[rcv[e]] + rank[e]] = make_int2(snd[e], e);
}

// fused: per 32-node tile, stage X (bf16) into A-tile cols 0..127, aggregate
// EF->Ae (A-tile cols 128..255) and P2->XJ, then one K=256 MFMA pass:
// out = [X|Ae]@[W1;We] + XJ + biases.
// phase A: whole wave per edge — csr via scalar load, lane owns 2 cols, no shuffles.
__global__ __launch_bounds__(512) void k_aggemm(
    const float* __restrict__ X, const float* __restrict__ EF,
    const unsigned short* __restrict__ P2, const unsigned* __restrict__ offs,
    const int2* __restrict__ csr, const unsigned short* __restrict__ BcTa,
    const float* __restrict__ bW, const float* __restrict__ bWe,
    float* __restrict__ out) {
    __shared__ unsigned short As[BM * 256];  // 16 KiB [32][256], XOR-swizzled
    __shared__ float XJ[BM][128];            // 16 KiB
    __shared__ float cf_s[BM];
    const int tid = threadIdx.x;
    const int w = tid >> 6, lane = tid & 63;
    const int m0 = blockIdx.x * BM;
    char* Asb = (char*)As;

    // ---- phase B first (independent bulk loads prefetch under phase A) ----
    // X -> A-tile cols 0..127: thread writes 4 bf16 = 8 BYTES at g*8 (row-stride 512 B).
    // (round-9 bug: g*16 left poison gaps and overlapped the Ae region -> NaN)
    for (int i = tid; i < BM * 32; i += 512) {
        int r = i >> 5, g = i & 31;
        int n = m0 + r;
        f32x4 v = {0.f, 0.f, 0.f, 0.f};
        if (n < NN) v = *reinterpret_cast<const f32x4*>(X + (size_t)n * DF + g * 4);
        unsigned pk0 = f2bf(v[0]) | (f2bf(v[1]) << 16);
        unsigned pk1 = f2bf(v[2]) | (f2bf(v[3]) << 16);
        unsigned byte = (unsigned)(r * 512 + g * 8) ^ ((unsigned)(r & 7) << 4);
        *reinterpret_cast<uint2*>(Asb + byte) = make_uint2(pk0, pk1);
    }

    // ---- phase A: wave owns 4 nodes; whole wave per edge ----
    {
        const int l2 = lane * 2;
        for (int t = 0; t < 4; ++t) {
            int r = w * 4 + t;
            int n = m0 + r;
            unsigned s0 = 0, s1 = 0;
            if (n < NN) { s0 = offs[n]; s1 = offs[n + 1]; }
            s0 = __builtin_amdgcn_readfirstlane(s0);
            s1 = __builtin_amdgcn_readfirstlane(s1);
            float efa = 0.f, efb = 0.f, xja = 0.f, xjb = 0.f;
#pragma unroll 8
            for (unsigned p = s0; p < s1; ++p) {
                int2 se = csr[p];  // wave-uniform -> scalar load
                float2 ev = *reinterpret_cast<const float2*>(EF + (size_t)se.y * DF + l2);
                unsigned pu = *reinterpret_cast<const unsigned*>(P2 + (size_t)se.x * DF + l2);
                efa += ev.x; efb += ev.y;
                xja += __uint_as_float(pu << 16);
                xjb += __uint_as_float(pu & 0xFFFF0000u);
            }
            float dg = (float)(s1 - s0);
            float inv = 1.0f / (dg + 1e-6f);
            // Ae -> A-tile cols 128..255 (bytes 256..511, disjoint from X's 0..255)
            unsigned pk = f2bf(efa * inv) | (f2bf(efb * inv) << 16);
            unsigned byte = (unsigned)(r * 512 + 256 + lane * 4) ^ ((unsigned)(r & 7) << 4);
            *reinterpret_cast<unsigned*>(Asb + byte) = pk;
            *reinterpret_cast<float2*>(&XJ[r][l2]) = make_float2(xja * inv, xjb * inv);
            if (lane == 0) cf_s[r] = dg * inv;
        }
    }
    __syncthreads();

    // ---- phase C: [X|Ae] @ BcTa^T; wave: 16 rows x 32 cols, K=256 ----
    {
        const int l15 = lane & 15, l4 = lane >> 4;
        const int h = w & 1;
        const int rrow = h * 16 + l15;
        const int n0 = (w >> 1) * 32;
        f32x4 acc0 = {0.f, 0.f, 0.f, 0.f}, acc1 = {0.f, 0.f, 0.f, 0.f};
        const unsigned rswz = (unsigned)(rrow & 7) << 4;
#pragma unroll
        for (int kk = 0; kk < 8; ++kk) {
            unsigned abyte = (unsigned)(rrow * 512 + (kk * 32 + l4 * 8) * 2) ^ rswz;
            bf16x8 a = *reinterpret_cast<const bf16x8*>(Asb + abyte);
            bf16x8 b0 = *reinterpret_cast<const bf16x8*>(
                BcTa + (size_t)(n0 + l15) * 256 + kk * 32 + l4 * 8);
            bf16x8 b1 = *reinterpret_cast<const bf16x8*>(
                BcTa + (size_t)(n0 + 16 + l15) * 256 + kk * 32 + l4 * 8);
            acc0 = __builtin_amdgcn_mfma_f32_16x16x32_bf16(a, b0, acc0, 0, 0, 0);
            acc1 = __builtin_amdgcn_mfma_f32_16x16x32_bf16(a, b1, acc1, 0, 0, 0);
        }
#pragma unroll
        for (int ng = 0; ng < 2; ++ng) {
            int col = n0 + ng * 16 + l15;
            float bx = bW[col];
            float bj = bW[128 + col] + bWe[col];
            f32x4 acc = ng ? acc1 : acc0;
#pragma unroll
            for (int j = 0; j < 4; ++j) {
                int lr = h * 16 + l4 * 4 + j;
                int row = m0 + lr;
                if (row < NN)
                    out[(size_t)row * DF + col] =
                        acc[j] + XJ[lr][col] + bx + cf_s[lr] * bj;
            }
        }
    }
}

extern "C" void kernel_launch(void* const* d_in, const int* in_sizes, int n_in,
                              void* d_out, int out_size, void* d_ws, size_t ws_size,
                              hipStream_t stream) {
    const float* X   = (const float*)d_in[0];
    const int*   snd = (const int*)d_in[1];
    const int*   rcv = (const int*)d_in[2];
    const float* EF  = (const float*)d_in[3];
    const float* W   = (const float*)d_in[4];
    const float* bW  = (const float*)d_in[5];
    const float* We  = (const float*)d_in[6];
    const float* bWe = (const float*)d_in[7];
    float* out = (float*)d_out;

    char* ws = (char*)d_ws;
    unsigned* deg  = (unsigned*)(ws + OFF_DEG);
    unsigned* offs = (unsigned*)(ws + OFF_OFFS);
    unsigned* part = (unsigned*)(ws + OFF_PART);
    unsigned* rank = (unsigned*)(ws + OFF_RANK);
    int2*     csr  = (int2*)(ws + OFF_CSR);
    unsigned short* BcTa = (unsigned short*)(ws + OFF_BCTA);
    unsigned short* W2T  = (unsigned short*)(ws + OFF_W2T);
    unsigned short* P2   = (unsigned short*)(ws + OFF_P2);

    k_setup<<<(NN + 255) / 256, 256, 0, stream>>>(W, We, deg, BcTa, W2T);
    k_gemm1hist<<<GB + HB, 256, 0, stream>>>(X, W2T, P2, rcv, deg, rank);
    k_scan1<<<SCAN_B, 256, 0, stream>>>(deg, part);
    k_scan2<<<1, 256, 0, stream>>>(part, offs);
    k_scan3<<<SCAN_B, 256, 0, stream>>>(deg, part, offs);
    k_scatter<<<(NE + 255) / 256, 256, 0, stream>>>(snd, rcv, offs, rank, csr);
    k_aggemm<<<NB, 512, 0, stream>>>(X, EF, P2, offs, csr, BcTa, bW, bWe, out);
}

// Round 11
// 199.173 us; speedup vs baseline: 1.8606x; 1.0677x over previous
//
#include <hip/hip_runtime.h>

#define NN 50000
#define NE 800000
#define DF 128
#define BM 32
#define NB ((NN + BM - 1) / BM)   // 1563
#define SCAN_B ((NN + 255) / 256) // 196
#define GB ((NN + 63) / 64)       // 782 gemm blocks
#define HB ((NE + 255) / 256)     // 3125 hist blocks

typedef __attribute__((ext_vector_type(8))) short bf16x8;
typedef __attribute__((ext_vector_type(4))) float f32x4;
typedef __attribute__((ext_vector_type(2))) float f32x2;

// ---- workspace layout (bytes) ----
static const size_t OFF_DEG  = 0;         // u32[NN]
static const size_t OFF_OFFS = 204800;    // u32[NN+1]
static const size_t OFF_PART = 409600;    // u32[SCAN_B]
static const size_t OFF_RANK = 614400;    // u32[NE]
static const size_t OFF_CSR  = 3814400;   // int2[NE]
static const size_t OFF_BCTA = 10214400;  // bf16[128][256]: [col][k], k<128=W1, k>=128=We
static const size_t OFF_W2T  = 10279936;  // bf16[128][128]: [col][k] = W[k][128+col]
static const size_t OFF_P2   = 10312704;  // bf16[NN][128] = bf16(X@W[:,128:])
// total ~23.1 MB

__device__ __forceinline__ unsigned f2bf(float f) {
    unsigned u = __float_as_uint(f);
    return (u + 0x7FFFu + ((u >> 16) & 1u)) >> 16;
}
// non-temporal 8B load: EF rows are touched exactly once by exactly one
// instruction -> no reuse to lose; keeps the 410MB stream from evicting P2.
__device__ __forceinline__ f32x2 ntload2(const float* p) {
    return __builtin_nontemporal_load(reinterpret_cast<const f32x2*>(p));
}

// zero deg + build BcTa (concat [W1; We] transposed) + W2T
__global__ void k_setup(const float* __restrict__ W, const float* __restrict__ We,
                        unsigned* __restrict__ deg, unsigned short* __restrict__ BcTa,
                        unsigned short* __restrict__ W2T) {
    int idx = blockIdx.x * blockDim.x + threadIdx.x;
    if (idx < NN) deg[idx] = 0;
    if (idx < 128 * 256) {
        int col = idx >> 8, k = idx & 255;
        float v = (k < 128) ? W[k * 256 + col] : We[(k - 128) * 128 + col];
        BcTa[idx] = (unsigned short)f2bf(v);
    }
    if (idx < 128 * 128) {
        int col = idx >> 7, k = idx & 127;
        W2T[idx] = (unsigned short)f2bf(W[k * 256 + 128 + col]);
    }
}

// blocks [0,GB): P2 = bf16(X@W[:,128:]); blocks [GB,GB+HB): degree hist + rank
__global__ __launch_bounds__(256) void k_gemm1hist(
    const float* __restrict__ X, const unsigned short* __restrict__ W2T,
    unsigned short* __restrict__ P2, const int* __restrict__ rcv,
    unsigned* __restrict__ deg, unsigned* __restrict__ rank) {
    __shared__ unsigned short As[64 * 128];  // 16 KiB, XOR-swizzled
    if (blockIdx.x >= GB) {
        int e = (blockIdx.x - GB) * 256 + threadIdx.x;
        if (e < NE) rank[e] = atomicAdd(&deg[rcv[e]], 1u);
        return;
    }
    const int tid = threadIdx.x;
    const int w = tid >> 6, lane = tid & 63;
    const int l15 = lane & 15, l4 = lane >> 4;
    const int m0 = blockIdx.x * 64;
    char* Asb = (char*)As;

    for (int i = tid; i < 64 * 32; i += 256) {
        int r = i >> 5, g = i & 31;
        int n = m0 + r;
        f32x4 v = {0.f, 0.f, 0.f, 0.f};
        if (n < NN) v = *reinterpret_cast<const f32x4*>(X + (size_t)n * DF + g * 4);
        unsigned pk0 = f2bf(v[0]) | (f2bf(v[1]) << 16);
        unsigned pk1 = f2bf(v[2]) | (f2bf(v[3]) << 16);
        unsigned byte = (unsigned)(r * 256 + g * 8) ^ ((unsigned)(r & 7) << 4);
        *reinterpret_cast<uint2*>(Asb + byte) = make_uint2(pk0, pk1);
    }
    __syncthreads();

    const int rrow = w * 16 + l15;
    const unsigned rswz = (unsigned)(rrow & 7) << 4;
    f32x4 acc[8];
#pragma unroll
    for (int ng = 0; ng < 8; ++ng) acc[ng] = (f32x4){0.f, 0.f, 0.f, 0.f};
#pragma unroll
    for (int kk = 0; kk < 4; ++kk) {
        unsigned abyte = (unsigned)(rrow * 256 + (kk * 32 + l4 * 8) * 2) ^ rswz;
        bf16x8 a = *reinterpret_cast<const bf16x8*>(Asb + abyte);
#pragma unroll
        for (int ng = 0; ng < 8; ++ng) {
            bf16x8 b = *reinterpret_cast<const bf16x8*>(
                W2T + (size_t)(ng * 16 + l15) * 128 + kk * 32 + l4 * 8);
            acc[ng] = __builtin_amdgcn_mfma_f32_16x16x32_bf16(a, b, acc[ng], 0, 0, 0);
        }
    }
#pragma unroll
    for (int ng = 0; ng < 8; ++ng) {
        int col = ng * 16 + l15;
#pragma unroll
        for (int j = 0; j < 4; ++j) {
            int row = m0 + w * 16 + l4 * 4 + j;
            if (row < NN) P2[(size_t)row * DF + col] = (unsigned short)f2bf(acc[ng][j]);
        }
    }
}

__global__ void k_scan1(const unsigned* __restrict__ deg, unsigned* __restrict__ part) {
    int idx = blockIdx.x * 256 + threadIdx.x;
    unsigned v = (idx < NN) ? deg[idx] : 0;
#pragma unroll
    for (int o = 32; o; o >>= 1) v += __shfl_down(v, o);
    __shared__ unsigned wsum[4];
    int w = threadIdx.x >> 6, lane = threadIdx.x & 63;
    if (lane == 0) wsum[w] = v;
    __syncthreads();
    if (threadIdx.x == 0) part[blockIdx.x] = wsum[0] + wsum[1] + wsum[2] + wsum[3];
}

// scan3 now also computes its own base from part[] (scan2 deleted):
// wave 0 sums part[0..b) while waves do the intra-block scan.
__global__ void k_scan3(const unsigned* __restrict__ deg, const unsigned* __restrict__ part,
                        unsigned* __restrict__ offs) {
    const int b = blockIdx.x;
    int idx = b * 256 + threadIdx.x;
    unsigned v = (idx < NN) ? deg[idx] : 0;
    int w = threadIdx.x >> 6, lane = threadIdx.x & 63;
    unsigned x = v;
#pragma unroll
    for (int o = 1; o < 64; o <<= 1) {
        unsigned y = __shfl_up(x, o);
        if (lane >= o) x += y;
    }
    __shared__ unsigned wsum[4];
    __shared__ unsigned base_s;
    if (lane == 63) wsum[w] = x;
    if (w == 0) {
        unsigned s = 0;
        for (int i = lane; i < b; i += 64) s += part[i];
#pragma unroll
        for (int o = 32; o; o >>= 1) s += __shfl_down(s, o);
        if (lane == 0) base_s = s;
    }
    __syncthreads();
    unsigned base = base_s;
    for (int i = 0; i < w; ++i) base += wsum[i];
    if (idx < NN) offs[idx] = base + x - v;
    // last thread of last block: total == NE (pad elements contribute 0)
    if (b == SCAN_B - 1 && threadIdx.x == 255) offs[NN] = base + x;
}

__global__ void k_scatter(const int* __restrict__ snd, const int* __restrict__ rcv,
                          const unsigned* __restrict__ offs, const unsigned* __restrict__ rank,
                          int2* __restrict__ csr) {
    int e = blockIdx.x * blockDim.x + threadIdx.x;
    if (e >= NE) return;
    csr[offs[rcv[e]] + rank[e]] = make_int2(snd[e], e);
}

// fused: per 32-node tile, stage X (bf16) into A-tile cols 0..127, aggregate
// EF->Ae (A-tile cols 128..255) and P2->XJ, then one K=256 MFMA pass:
// out = [X|Ae]@[W1;We] + XJ + biases.
// phase A: whole wave per edge — csr via scalar load, lane owns 2 cols, no shuffles.
__global__ __launch_bounds__(512) void k_aggemm(
    const float* __restrict__ X, const float* __restrict__ EF,
    const unsigned short* __restrict__ P2, const unsigned* __restrict__ offs,
    const int2* __restrict__ csr, const unsigned short* __restrict__ BcTa,
    const float* __restrict__ bW, const float* __restrict__ bWe,
    float* __restrict__ out) {
    __shared__ unsigned short As[BM * 256];  // 16 KiB [32][256], XOR-swizzled
    __shared__ float XJ[BM][128];            // 16 KiB
    __shared__ float cf_s[BM];
    const int tid = threadIdx.x;
    const int w = tid >> 6, lane = tid & 63;
    const int m0 = blockIdx.x * BM;
    char* Asb = (char*)As;

    // ---- phase B first (independent bulk loads prefetch under phase A) ----
    for (int i = tid; i < BM * 32; i += 512) {
        int r = i >> 5, g = i & 31;
        int n = m0 + r;
        f32x4 v = {0.f, 0.f, 0.f, 0.f};
        if (n < NN) v = *reinterpret_cast<const f32x4*>(X + (size_t)n * DF + g * 4);
        unsigned pk0 = f2bf(v[0]) | (f2bf(v[1]) << 16);
        unsigned pk1 = f2bf(v[2]) | (f2bf(v[3]) << 16);
        unsigned byte = (unsigned)(r * 512 + g * 8) ^ ((unsigned)(r & 7) << 4);
        *reinterpret_cast<uint2*>(Asb + byte) = make_uint2(pk0, pk1);
    }

    // ---- phase A: wave owns 4 nodes; whole wave per edge ----
    {
        const int l2 = lane * 2;
        for (int t = 0; t < 4; ++t) {
            int r = w * 4 + t;
            int n = m0 + r;
            unsigned s0 = 0, s1 = 0;
            if (n < NN) { s0 = offs[n]; s1 = offs[n + 1]; }
            s0 = __builtin_amdgcn_readfirstlane(s0);
            s1 = __builtin_amdgcn_readfirstlane(s1);
            float efa = 0.f, efb = 0.f, xja = 0.f, xjb = 0.f;
#pragma unroll 8
            for (unsigned p = s0; p < s1; ++p) {
                int2 se = csr[p];  // wave-uniform -> scalar load
                f32x2 ev = ntload2(EF + (size_t)se.y * DF + l2);  // nt: stream, no reuse
                unsigned pu = *reinterpret_cast<const unsigned*>(P2 + (size_t)se.x * DF + l2);
                efa += ev[0]; efb += ev[1];
                xja += __uint_as_float(pu << 16);
                xjb += __uint_as_float(pu & 0xFFFF0000u);
            }
            float dg = (float)(s1 - s0);
            float inv = 1.0f / (dg + 1e-6f);
            // Ae -> A-tile cols 128..255 (bytes 256..511, disjoint from X's 0..255)
            unsigned pk = f2bf(efa * inv) | (f2bf(efb * inv) << 16);
            unsigned byte = (unsigned)(r * 512 + 256 + lane * 4) ^ ((unsigned)(r & 7) << 4);
            *reinterpret_cast<unsigned*>(Asb + byte) = pk;
            *reinterpret_cast<float2*>(&XJ[r][l2]) = make_float2(xja * inv, xjb * inv);
            if (lane == 0) cf_s[r] = dg * inv;
        }
    }
    __syncthreads();

    // ---- phase C: [X|Ae] @ BcTa^T; wave: 16 rows x 32 cols, K=256 ----
    {
        const int l15 = lane & 15, l4 = lane >> 4;
        const int h = w & 1;
        const int rrow = h * 16 + l15;
        const int n0 = (w >> 1) * 32;
        f32x4 acc0 = {0.f, 0.f, 0.f, 0.f}, acc1 = {0.f, 0.f, 0.f, 0.f};
        const unsigned rswz = (unsigned)(rrow & 7) << 4;
#pragma unroll
        for (int kk = 0; kk < 8; ++kk) {
            unsigned abyte = (unsigned)(rrow * 512 + (kk * 32 + l4 * 8) * 2) ^ rswz;
            bf16x8 a = *reinterpret_cast<const bf16x8*>(Asb + abyte);
            bf16x8 b0 = *reinterpret_cast<const bf16x8*>(
                BcTa + (size_t)(n0 + l15) * 256 + kk * 32 + l4 * 8);
            bf16x8 b1 = *reinterpret_cast<const bf16x8*>(
                BcTa + (size_t)(n0 + 16 + l15) * 256 + kk * 32 + l4 * 8);
            acc0 = __builtin_amdgcn_mfma_f32_16x16x32_bf16(a, b0, acc0, 0, 0, 0);
            acc1 = __builtin_amdgcn_mfma_f32_16x16x32_bf16(a, b1, acc1, 0, 0, 0);
        }
#pragma unroll
        for (int ng = 0; ng < 2; ++ng) {
            int col = n0 + ng * 16 + l15;
            float bx = bW[col];
            float bj = bW[128 + col] + bWe[col];
            f32x4 acc = ng ? acc1 : acc0;
#pragma unroll
            for (int j = 0; j < 4; ++j) {
                int lr = h * 16 + l4 * 4 + j;
                int row = m0 + lr;
                if (row < NN)
                    out[(size_t)row * DF + col] =
                        acc[j] + XJ[lr][col] + bx + cf_s[lr] * bj;
            }
        }
    }
}

extern "C" void kernel_launch(void* const* d_in, const int* in_sizes, int n_in,
                              void* d_out, int out_size, void* d_ws, size_t ws_size,
                              hipStream_t stream) {
    const float* X   = (const float*)d_in[0];
    const int*   snd = (const int*)d_in[1];
    const int*   rcv = (const int*)d_in[2];
    const float* EF  = (const float*)d_in[3];
    const float* W   = (const float*)d_in[4];
    const float* bW  = (const float*)d_in[5];
    const float* We  = (const float*)d_in[6];
    const float* bWe = (const float*)d_in[7];
    float* out = (float*)d_out;

    char* ws = (char*)d_ws;
    unsigned* deg  = (unsigned*)(ws + OFF_DEG);
    unsigned* offs = (unsigned*)(ws + OFF_OFFS);
    unsigned* part = (unsigned*)(ws + OFF_PART);
    unsigned* rank = (unsigned*)(ws + OFF_RANK);
    int2*     csr  = (int2*)(ws + OFF_CSR);
    unsigned short* BcTa = (unsigned short*)(ws + OFF_BCTA);
    unsigned short* W2T  = (unsigned short*)(ws + OFF_W2T);
    unsigned short* P2   = (unsigned short*)(ws + OFF_P2);

    k_setup<<<(NN + 255) / 256, 256, 0, stream>>>(W, We, deg, BcTa, W2T);
    k_gemm1hist<<<GB + HB, 256, 0, stream>>>(X, W2T, P2, rcv, deg, rank);
    k_scan1<<<SCAN_B, 256, 0, stream>>>(deg, part);
    k_scan3<<<SCAN_B, 256, 0, stream>>>(deg, part, offs);
    k_scatter<<<(NE + 255) / 256, 256, 0, stream>>>(snd, rcv, offs, rank, csr);
    k_aggemm<<<NB, 512, 0, stream>>>(X, EF, P2, offs, csr, BcTa, bW, bWe, out);
}

// Round 12
// 196.146 us; speedup vs baseline: 1.8893x; 1.0154x over previous
//
#include <hip/hip_runtime.h>

#define NN 50000
#define NE 800000
#define DF 128
#define BM 32
#define NB ((NN + BM - 1) / BM)   // 1563
#define SCAN_B ((NN + 255) / 256) // 196
#define GB ((NN + 63) / 64)       // 782 gemm blocks
#define HB ((NE + 255) / 256)     // 3125 hist blocks

typedef __attribute__((ext_vector_type(8))) short bf16x8;
typedef __attribute__((ext_vector_type(4))) float f32x4;
typedef __attribute__((ext_vector_type(2))) float f32x2;

// ---- workspace layout (bytes) ----
static const size_t OFF_DEG  = 0;         // u32[NN]
static const size_t OFF_OFFS = 204800;    // u32[NN+1]
static const size_t OFF_PART = 409600;    // u32[SCAN_B]
static const size_t OFF_RANK = 614400;    // u32[NE]
static const size_t OFF_CSR  = 3814400;   // int2[NE]
static const size_t OFF_BCTA = 10214400;  // bf16[128][256]: [col][k], k<128=W1, k>=128=We
static const size_t OFF_W2T  = 10279936;  // bf16[128][128]: [col][k] = W[k][128+col]
static const size_t OFF_P2   = 10312704;  // bf16[NN][128] = bf16(X@W[:,128:])
// total ~23.1 MB

__device__ __forceinline__ unsigned f2bf(float f) {
    unsigned u = __float_as_uint(f);
    return (u + 0x7FFFu + ((u >> 16) & 1u)) >> 16;
}
// non-temporal: EF rows are touched exactly once -> keep the 410MB stream
// from evicting the P2 gather table.
__device__ __forceinline__ f32x2 ntload2(const float* p) {
    return __builtin_nontemporal_load(reinterpret_cast<const f32x2*>(p));
}

// zero deg + build BcTa (concat [W1; We] transposed) + W2T
__global__ void k_setup(const float* __restrict__ W, const float* __restrict__ We,
                        unsigned* __restrict__ deg, unsigned short* __restrict__ BcTa,
                        unsigned short* __restrict__ W2T) {
    int idx = blockIdx.x * blockDim.x + threadIdx.x;
    if (idx < NN) deg[idx] = 0;
    if (idx < 128 * 256) {
        int col = idx >> 8, k = idx & 255;
        float v = (k < 128) ? W[k * 256 + col] : We[(k - 128) * 128 + col];
        BcTa[idx] = (unsigned short)f2bf(v);
    }
    if (idx < 128 * 128) {
        int col = idx >> 7, k = idx & 127;
        W2T[idx] = (unsigned short)f2bf(W[k * 256 + 128 + col]);
    }
}

// blocks [0,GB): P2 = bf16(X@W[:,128:]); blocks [GB,GB+HB): degree hist + rank
__global__ __launch_bounds__(256) void k_gemm1hist(
    const float* __restrict__ X, const unsigned short* __restrict__ W2T,
    unsigned short* __restrict__ P2, const int* __restrict__ rcv,
    unsigned* __restrict__ deg, unsigned* __restrict__ rank) {
    __shared__ unsigned short As[64 * 128];  // 16 KiB, XOR-swizzled
    if (blockIdx.x >= GB) {
        int e = (blockIdx.x - GB) * 256 + threadIdx.x;
        if (e < NE) rank[e] = atomicAdd(&deg[rcv[e]], 1u);
        return;
    }
    const int tid = threadIdx.x;
    const int w = tid >> 6, lane = tid & 63;
    const int l15 = lane & 15, l4 = lane >> 4;
    const int m0 = blockIdx.x * 64;
    char* Asb = (char*)As;

    for (int i = tid; i < 64 * 32; i += 256) {
        int r = i >> 5, g = i & 31;
        int n = m0 + r;
        f32x4 v = {0.f, 0.f, 0.f, 0.f};
        if (n < NN) v = *reinterpret_cast<const f32x4*>(X + (size_t)n * DF + g * 4);
        unsigned pk0 = f2bf(v[0]) | (f2bf(v[1]) << 16);
        unsigned pk1 = f2bf(v[2]) | (f2bf(v[3]) << 16);
        unsigned byte = (unsigned)(r * 256 + g * 8) ^ ((unsigned)(r & 7) << 4);
        *reinterpret_cast<uint2*>(Asb + byte) = make_uint2(pk0, pk1);
    }
    __syncthreads();

    const int rrow = w * 16 + l15;
    const unsigned rswz = (unsigned)(rrow & 7) << 4;
    f32x4 acc[8];
#pragma unroll
    for (int ng = 0; ng < 8; ++ng) acc[ng] = (f32x4){0.f, 0.f, 0.f, 0.f};
#pragma unroll
    for (int kk = 0; kk < 4; ++kk) {
        unsigned abyte = (unsigned)(rrow * 256 + (kk * 32 + l4 * 8) * 2) ^ rswz;
        bf16x8 a = *reinterpret_cast<const bf16x8*>(Asb + abyte);
#pragma unroll
        for (int ng = 0; ng < 8; ++ng) {
            bf16x8 b = *reinterpret_cast<const bf16x8*>(
                W2T + (size_t)(ng * 16 + l15) * 128 + kk * 32 + l4 * 8);
            acc[ng] = __builtin_amdgcn_mfma_f32_16x16x32_bf16(a, b, acc[ng], 0, 0, 0);
        }
    }
#pragma unroll
    for (int ng = 0; ng < 8; ++ng) {
        int col = ng * 16 + l15;
#pragma unroll
        for (int j = 0; j < 4; ++j) {
            int row = m0 + w * 16 + l4 * 4 + j;
            if (row < NN) P2[(size_t)row * DF + col] = (unsigned short)f2bf(acc[ng][j]);
        }
    }
}

__global__ void k_scan1(const unsigned* __restrict__ deg, unsigned* __restrict__ part) {
    int idx = blockIdx.x * 256 + threadIdx.x;
    unsigned v = (idx < NN) ? deg[idx] : 0;
#pragma unroll
    for (int o = 32; o; o >>= 1) v += __shfl_down(v, o);
    __shared__ unsigned wsum[4];
    int w = threadIdx.x >> 6, lane = threadIdx.x & 63;
    if (lane == 0) wsum[w] = v;
    __syncthreads();
    if (threadIdx.x == 0) part[blockIdx.x] = wsum[0] + wsum[1] + wsum[2] + wsum[3];
}

// scan3 computes its own base from part[] (wave 0) + intra-block scan
__global__ void k_scan3(const unsigned* __restrict__ deg, const unsigned* __restrict__ part,
                        unsigned* __restrict__ offs) {
    const int b = blockIdx.x;
    int idx = b * 256 + threadIdx.x;
    unsigned v = (idx < NN) ? deg[idx] : 0;
    int w = threadIdx.x >> 6, lane = threadIdx.x & 63;
    unsigned x = v;
#pragma unroll
    for (int o = 1; o < 64; o <<= 1) {
        unsigned y = __shfl_up(x, o);
        if (lane >= o) x += y;
    }
    __shared__ unsigned wsum[4];
    __shared__ unsigned base_s;
    if (lane == 63) wsum[w] = x;
    if (w == 0) {
        unsigned s = 0;
        for (int i = lane; i < b; i += 64) s += part[i];
#pragma unroll
        for (int o = 32; o; o >>= 1) s += __shfl_down(s, o);
        if (lane == 0) base_s = s;
    }
    __syncthreads();
    unsigned base = base_s;
    for (int i = 0; i < w; ++i) base += wsum[i];
    if (idx < NN) offs[idx] = base + x - v;
    if (b == SCAN_B - 1 && threadIdx.x == 255) offs[NN] = base + x;
}

__global__ void k_scatter(const int* __restrict__ snd, const int* __restrict__ rcv,
                          const unsigned* __restrict__ offs, const unsigned* __restrict__ rank,
                          int2* __restrict__ csr) {
    int e = blockIdx.x * blockDim.x + threadIdx.x;
    if (e >= NE) return;
    csr[offs[rcv[e]] + rank[e]] = make_int2(snd[e], e);
}

// fused: per 32-node tile, stage X (bf16) into A-tile cols 0..127, aggregate
// EF->Ae (A-tile cols 128..255) and P2->XJ, then one K=256 MFMA pass:
// out = [X|Ae]@[W1;We] + XJ + biases.
// phase A: whole wave per edge, MASKED-PADDED to multiples of 8 so every edge
// load lives in a fully-unrolled body (no rolled-remainder dependent chains).
__global__ __launch_bounds__(512) void k_aggemm(
    const float* __restrict__ X, const float* __restrict__ EF,
    const unsigned short* __restrict__ P2, const unsigned* __restrict__ offs,
    const int2* __restrict__ csr, const unsigned short* __restrict__ BcTa,
    const float* __restrict__ bW, const float* __restrict__ bWe,
    float* __restrict__ out) {
    __shared__ unsigned short As[BM * 256];  // 16 KiB [32][256], XOR-swizzled
    __shared__ float XJ[BM][132];            // padded stride: bank-conflict-free epilogue
    __shared__ float cf_s[BM];
    const int tid = threadIdx.x;
    const int w = tid >> 6, lane = tid & 63;
    const int m0 = blockIdx.x * BM;
    char* Asb = (char*)As;

    // ---- phase B first (independent bulk loads prefetch under phase A) ----
    for (int i = tid; i < BM * 32; i += 512) {
        int r = i >> 5, g = i & 31;
        int n = m0 + r;
        f32x4 v = {0.f, 0.f, 0.f, 0.f};
        if (n < NN) v = *reinterpret_cast<const f32x4*>(X + (size_t)n * DF + g * 4);
        unsigned pk0 = f2bf(v[0]) | (f2bf(v[1]) << 16);
        unsigned pk1 = f2bf(v[2]) | (f2bf(v[3]) << 16);
        unsigned byte = (unsigned)(r * 512 + g * 8) ^ ((unsigned)(r & 7) << 4);
        *reinterpret_cast<uint2*>(Asb + byte) = make_uint2(pk0, pk1);
    }

    // ---- phase A: wave owns 4 nodes; whole wave per edge ----
    {
        const int l2 = lane * 2;
        for (int t = 0; t < 4; ++t) {
            int r = w * 4 + t;
            int n = m0 + r;
            unsigned s0 = 0, s1 = 0;
            if (n < NN) { s0 = offs[n]; s1 = offs[n + 1]; }
            s0 = __builtin_amdgcn_readfirstlane(s0);
            s1 = __builtin_amdgcn_readfirstlane(s1);
            unsigned dg = s1 - s0;
            float efa = 0.f, efb = 0.f, xja = 0.f, xjb = 0.f;
            unsigned nb = (dg + 7) >> 3;  // 8-edge bodies, masked tail
            unsigned p = s0;
            for (unsigned bdy = 0; bdy < nb; ++bdy, p += 8) {
#pragma unroll
                for (int i = 0; i < 8; ++i) {
                    unsigned pe = p + i;
                    bool act = pe < s1;
                    unsigned pc = act ? pe : s0;  // masked-off: re-read s0 (L1 hit)
                    int2 se = csr[pc];            // wave-uniform -> scalar load
                    f32x2 ev = ntload2(EF + (size_t)se.y * DF + l2);
                    unsigned pu = *reinterpret_cast<const unsigned*>(
                        P2 + (size_t)se.x * DF + l2);
                    float m = act ? 1.f : 0.f;
                    efa += m * ev[0]; efb += m * ev[1];
                    xja += m * __uint_as_float(pu << 16);
                    xjb += m * __uint_as_float(pu & 0xFFFF0000u);
                }
            }
            float dgf = (float)dg;
            float inv = 1.0f / (dgf + 1e-6f);
            unsigned pk = f2bf(efa * inv) | (f2bf(efb * inv) << 16);
            unsigned byte = (unsigned)(r * 512 + 256 + lane * 4) ^ ((unsigned)(r & 7) << 4);
            *reinterpret_cast<unsigned*>(Asb + byte) = pk;
            *reinterpret_cast<float2*>(&XJ[r][l2]) = make_float2(xja * inv, xjb * inv);
            if (lane == 0) cf_s[r] = dgf * inv;
        }
    }
    __syncthreads();

    // ---- phase C: [X|Ae] @ BcTa^T; wave: 16 rows x 32 cols, K=256 ----
    {
        const int l15 = lane & 15, l4 = lane >> 4;
        const int h = w & 1;
        const int rrow = h * 16 + l15;
        const int n0 = (w >> 1) * 32;
        f32x4 acc0 = {0.f, 0.f, 0.f, 0.f}, acc1 = {0.f, 0.f, 0.f, 0.f};
        const unsigned rswz = (unsigned)(rrow & 7) << 4;
#pragma unroll
        for (int kk = 0; kk < 8; ++kk) {
            unsigned abyte = (unsigned)(rrow * 512 + (kk * 32 + l4 * 8) * 2) ^ rswz;
            bf16x8 a = *reinterpret_cast<const bf16x8*>(Asb + abyte);
            bf16x8 b0 = *reinterpret_cast<const bf16x8*>(
                BcTa + (size_t)(n0 + l15) * 256 + kk * 32 + l4 * 8);
            bf16x8 b1 = *reinterpret_cast<const bf16x8*>(
                BcTa + (size_t)(n0 + 16 + l15) * 256 + kk * 32 + l4 * 8);
            acc0 = __builtin_amdgcn_mfma_f32_16x16x32_bf16(a, b0, acc0, 0, 0, 0);
            acc1 = __builtin_amdgcn_mfma_f32_16x16x32_bf16(a, b1, acc1, 0, 0, 0);
        }
#pragma unroll
        for (int ng = 0; ng < 2; ++ng) {
            int col = n0 + ng * 16 + l15;
            float bx = bW[col];
            float bj = bW[128 + col] + bWe[col];
            f32x4 acc = ng ? acc1 : acc0;
#pragma unroll
            for (int j = 0; j < 4; ++j) {
                int lr = h * 16 + l4 * 4 + j;
                int row = m0 + lr;
                if (row < NN) {
                    float o = acc[j] + XJ[lr][col] + bx + cf_s[lr] * bj;
                    // nt store: out is written once, never re-read -> don't
                    // evict P2/X from L2/L3
                    __builtin_nontemporal_store(o, &out[(size_t)row * DF + col]);
                }
            }
        }
    }
}

extern "C" void kernel_launch(void* const* d_in, const int* in_sizes, int n_in,
                              void* d_out, int out_size, void* d_ws, size_t ws_size,
                              hipStream_t stream) {
    const float* X   = (const float*)d_in[0];
    const int*   snd = (const int*)d_in[1];
    const int*   rcv = (const int*)d_in[2];
    const float* EF  = (const float*)d_in[3];
    const float* W   = (const float*)d_in[4];
    const float* bW  = (const float*)d_in[5];
    const float* We  = (const float*)d_in[6];
    const float* bWe = (const float*)d_in[7];
    float* out = (float*)d_out;

    char* ws = (char*)d_ws;
    unsigned* deg  = (unsigned*)(ws + OFF_DEG);
    unsigned* offs = (unsigned*)(ws + OFF_OFFS);
    unsigned* part = (unsigned*)(ws + OFF_PART);
    unsigned* rank = (unsigned*)(ws + OFF_RANK);
    int2*     csr  = (int2*)(ws + OFF_CSR);
    unsigned short* BcTa = (unsigned short*)(ws + OFF_BCTA);
    unsigned short* W2T  = (unsigned short*)(ws + OFF_W2T);
    unsigned short* P2   = (unsigned short*)(ws + OFF_P2);

    k_setup<<<(NN + 255) / 256, 256, 0, stream>>>(W, We, deg, BcTa, W2T);
    k_gemm1hist<<<GB + HB, 256, 0, stream>>>(X, W2T, P2, rcv, deg, rank);
    k_scan1<<<SCAN_B, 256, 0, stream>>>(deg, part);
    k_scan3<<<SCAN_B, 256, 0, stream>>>(deg, part, offs);
    k_scatter<<<(NE + 255) / 256, 256, 0, stream>>>(snd, rcv, offs, rank, csr);
    k_aggemm<<<NB, 512, 0, stream>>>(X, EF, P2, offs, csr, BcTa, bW, bWe, out);
}